// Round 12
// baseline (117.720 us; speedup 1.0000x reference)
//
#include <hip/hip_runtime.h>
#include <hip/hip_bf16.h>
#include <stdint.h>
#include <stddef.h>

#define B_ 2
#define T_ 2048
#define C_ 1024
#define H_ 16
#define D_ 64
#define M_ (B_*T_)   // 4096

typedef __attribute__((ext_vector_type(8))) short short8;
typedef __attribute__((ext_vector_type(4))) float f32x4;
typedef __attribute__((ext_vector_type(16))) float f32x16;
typedef __attribute__((ext_vector_type(4))) unsigned int u32x4;

__device__ __forceinline__ unsigned short f2bf(float f) {
    unsigned u = __float_as_uint(f);
    unsigned r = 0x7FFFu + ((u >> 16) & 1u);
    return (unsigned short)((u + r) >> 16);
}

__device__ __forceinline__ unsigned cvtpk_bf16(float lo, float hi) {
    unsigned r;
    asm("v_cvt_pk_bf16_f32 %0, %1, %2" : "=v"(r) : "v"(lo), "v"(hi));
    return r;
}

// guaranteed single-instruction 2^x
__device__ __forceinline__ float fexp2(float x) {
    float r;
    asm("v_exp_f32 %0, %1" : "=v"(r) : "v"(x));
    return r;
}

// v_permlane32_swap_b32: a = [a_lo | b_lo], b = [a_hi | b_hi]
__device__ __forceinline__ void plswap(unsigned &a, unsigned &b) {
    asm("v_permlane32_swap_b32 %0, %1" : "+v"(a), "+v"(b));
}

__device__ __forceinline__ float xhalf_max(float v) {
    float a = v, b = v;
    asm("" : "+v"(b));
    asm("v_permlane32_swap_b32 %0, %1" : "+v"(a), "+v"(b));
    return fmaxf(a, b);
}
__device__ __forceinline__ float xhalf_sum(float v) {
    float a = v, b = v;
    asm("" : "+v"(b));
    asm("v_permlane32_swap_b32 %0, %1" : "+v"(a), "+v"(b));
    return a + b;
}

__device__ __forceinline__ void gload16(const void* g, void* l) {
    __builtin_amdgcn_global_load_lds(
        (__attribute__((address_space(1))) void*)g,
        (__attribute__((address_space(3))) void*)l,
        16, 0, 0);
}

// ---------------- fp32 -> bf16 conversion: all 5 tensors, one launch ----------------
// layout: [x: 4M][Wk: 1M][Wq: 1M][Wv: 1M][Wo: 1M] = 8M elements
__global__ void cvt_all(const float* __restrict__ x,  const float* __restrict__ wk,
                        const float* __restrict__ wq, const float* __restrict__ wv,
                        const float* __restrict__ wo,
                        unsigned short* __restrict__ xb,  unsigned short* __restrict__ wkb,
                        unsigned short* __restrict__ wqb, unsigned short* __restrict__ wvb,
                        unsigned short* __restrict__ wob) {
    int idx = (blockIdx.x * blockDim.x + threadIdx.x) * 4;
    const float* in; unsigned short* out; int off;
    if      (idx < (4<<20)) { in = x;  out = xb;  off = idx; }
    else if (idx < (5<<20)) { in = wk; out = wkb; off = idx - (4<<20); }
    else if (idx < (6<<20)) { in = wq; out = wqb; off = idx - (5<<20); }
    else if (idx < (7<<20)) { in = wv; out = wvb; off = idx - (6<<20); }
    else                    { in = wo; out = wob; off = idx - (7<<20); }
    float4 v = *reinterpret_cast<const float4*>(in + off);
    ushort4 o;
    o.x = f2bf(v.x); o.y = f2bf(v.y); o.z = f2bf(v.z); o.w = f2bf(v.w);
    *reinterpret_cast<ushort4*>(out + off) = o;
}

// ---------------- fused QKV projection GEMM (R9-verified: BK=32) ----------------
// which 0 -> K [B,H,T,D], which 1 -> Q*scale [B,H,T,D], which 2 -> V^T [B,H,D,T]
__global__ __launch_bounds__(256) void gemm_qkv(
    const unsigned short* __restrict__ A,
    const unsigned short* __restrict__ W0,
    const unsigned short* __restrict__ W1,
    const unsigned short* __restrict__ W2,
    const float* __restrict__ b0,
    const float* __restrict__ b1,
    const float* __restrict__ b2,
    unsigned short* __restrict__ o0,   // k
    unsigned short* __restrict__ o1,   // q (pre-scaled by LOG2E/32)
    unsigned short* __restrict__ o2)   // vt
{
    __shared__ unsigned short As[128*32];
    __shared__ unsigned short Bs[128*32];
    int which = blockIdx.x >> 8;
    int bx = blockIdx.x & 255;
    int bm = bx >> 3, bn = bx & 7;
    const unsigned short* W = (which==0) ? W0 : ((which==1) ? W1 : W2);
    const float* bias = (which==0) ? b0 : ((which==1) ? b1 : b2);

    int tid = threadIdx.x;
    int lane = tid & 63;
    int fr = lane & 15, fq = lane >> 4;
    int wid = tid >> 6;
    int wr = wid >> 1, wc = wid & 1;

    int srow = tid >> 2;            // 0..63
    int scol = (tid & 3) << 3;      // 0,8,16,24
    const unsigned short* Ab = A + (size_t)(bm*128 + srow) * C_ + scol;
    const unsigned short* Wb = W + (size_t)(bn*128 + srow) * C_ + scol;

    f32x4 acc[4][4] = {};

    for (int kt = 0; kt < C_/32; ++kt) {
        int ko = kt*32;
        gload16(Ab + ko,            &As[tid*8]);
        gload16(Ab + 64*C_ + ko,    &As[2048 + tid*8]);
        gload16(Wb + ko,            &Bs[tid*8]);
        gload16(Wb + 64*C_ + ko,    &Bs[2048 + tid*8]);
        __syncthreads();
        short8 af[4], bfr[4];
        #pragma unroll
        for (int i = 0; i < 4; ++i) {
            af[i]  = *reinterpret_cast<const short8*>(&As[(wr*64 + i*16 + fr)*32 + fq*8]);
            bfr[i] = *reinterpret_cast<const short8*>(&Bs[(wc*64 + i*16 + fr)*32 + fq*8]);
        }
        #pragma unroll
        for (int i = 0; i < 4; ++i)
            #pragma unroll
            for (int j = 0; j < 4; ++j)
                acc[i][j] = __builtin_amdgcn_mfma_f32_16x16x32_bf16(af[i], bfr[j], acc[i][j], 0, 0, 0);
        __syncthreads();
    }

    // Q: fold 1/sqrt(C)=1/32 AND log2(e) so QK^T lands in log2 domain
    float sc = (which == 1) ? 0.045084220f : 1.0f;
    int mbase = bm*128 + wr*64;
    int nbase = bn*128 + wc*64;
    #pragma unroll
    for (int j = 0; j < 4; ++j) {
        int col = nbase + j*16 + fr;
        float bv = bias[col];
        int h = col >> 6, d = col & 63;
        #pragma unroll
        for (int i = 0; i < 4; ++i) {
            int r0 = mbase + i*16 + fq*4;
            #pragma unroll
            for (int r = 0; r < 4; ++r) {
                float v = (acc[i][j][r] + bv) * sc;
                int m = r0 + r;
                int b = m >> 11, t = m & (T_-1);
                unsigned short hv = f2bf(v);
                if (which == 2)
                    o2[((size_t)(b*H_ + h)*D_ + d)*T_ + t] = hv;
                else {
                    unsigned short* o = (which==0) ? o0 : o1;
                    o[((size_t)(b*H_ + h)*T_ + t)*D_ + d] = hv;
                }
            }
        }
    }
}

// ---------------- output projection GEMM (R9-verified: BK=32) ----------------
__global__ __launch_bounds__(256) void gemm_out(
    const unsigned short* __restrict__ A,   // y bf16 [M_][C_]
    const unsigned short* __restrict__ W,   // Wo bf16 [C_][C_]
    const float* __restrict__ bias,
    float* __restrict__ out)
{
    __shared__ unsigned short As[128*32];
    __shared__ unsigned short Bs[128*32];
    int bx = blockIdx.x;
    int bm = bx >> 3, bn = bx & 7;

    int tid = threadIdx.x;
    int lane = tid & 63;
    int fr = lane & 15, fq = lane >> 4;
    int wid = tid >> 6;
    int wr = wid >> 1, wc = wid & 1;

    int srow = tid >> 2;
    int scol = (tid & 3) << 3;
    const unsigned short* Ab = A + (size_t)(bm*128 + srow) * C_ + scol;
    const unsigned short* Wb = W + (size_t)(bn*128 + srow) * C_ + scol;

    f32x4 acc[4][4] = {};

    for (int kt = 0; kt < C_/32; ++kt) {
        int ko = kt*32;
        gload16(Ab + ko,            &As[tid*8]);
        gload16(Ab + 64*C_ + ko,    &As[2048 + tid*8]);
        gload16(Wb + ko,            &Bs[tid*8]);
        gload16(Wb + 64*C_ + ko,    &Bs[2048 + tid*8]);
        __syncthreads();
        short8 af[4], bfr[4];
        #pragma unroll
        for (int i = 0; i < 4; ++i) {
            af[i]  = *reinterpret_cast<const short8*>(&As[(wr*64 + i*16 + fr)*32 + fq*8]);
            bfr[i] = *reinterpret_cast<const short8*>(&Bs[(wc*64 + i*16 + fr)*32 + fq*8]);
        }
        #pragma unroll
        for (int i = 0; i < 4; ++i)
            #pragma unroll
            for (int j = 0; j < 4; ++j)
                acc[i][j] = __builtin_amdgcn_mfma_f32_16x16x32_bf16(af[i], bfr[j], acc[i][j], 0, 0, 0);
        __syncthreads();
    }

    int mbase = bm*128 + wr*64;
    int nbase = bn*128 + wc*64;
    #pragma unroll
    for (int j = 0; j < 4; ++j) {
        int col = nbase + j*16 + fr;
        float bv = bias[col];
        #pragma unroll
        for (int i = 0; i < 4; ++i) {
            int r0 = mbase + i*16 + fq*4;
            #pragma unroll
            for (int r = 0; r < 4; ++r)
                out[(size_t)(r0 + r)*C_ + col] = acc[i][j][r] + bv;
        }
    }
}

// ---------------- flash attention: staged, 2-way KV split, dual-chain ILP ----------------
// Both q-chains processed unconditionally per subtile with a branchless arithmetic
// causal mask; m sentinel = -1e29 (> mask -1e30) makes fully-masked tiles contribute 0.
__device__ __forceinline__ void attn_subtile2(
    const short8 (&kf)[4], const short8 (&qf0)[4], const short8 (&qf1)[4],
    const short8 (&vlo)[2], const short8 (&vhi)[2],
    int dg0, int l31, int hi,
    f32x16& o00, f32x16& o01, float& m0, float& l0,
    f32x16& o10, f32x16& o11, float& m1, float& l1)
{
    int dg1 = dg0 - 32;

    // QK^T both chains; each split into 2 independent MFMA chains (4 total)
    f32x16 aA = {}, aB = {}, bA = {}, bB = {};
    __builtin_amdgcn_s_setprio(1);
    aA = __builtin_amdgcn_mfma_f32_32x32x16_bf16(kf[0], qf0[0], aA, 0, 0, 0);
    bA = __builtin_amdgcn_mfma_f32_32x32x16_bf16(kf[0], qf1[0], bA, 0, 0, 0);
    aB = __builtin_amdgcn_mfma_f32_32x32x16_bf16(kf[1], qf0[1], aB, 0, 0, 0);
    bB = __builtin_amdgcn_mfma_f32_32x32x16_bf16(kf[1], qf1[1], bB, 0, 0, 0);
    aA = __builtin_amdgcn_mfma_f32_32x32x16_bf16(kf[2], qf0[2], aA, 0, 0, 0);
    bA = __builtin_amdgcn_mfma_f32_32x32x16_bf16(kf[2], qf1[2], bA, 0, 0, 0);
    aB = __builtin_amdgcn_mfma_f32_32x32x16_bf16(kf[3], qf0[3], aB, 0, 0, 0);
    bB = __builtin_amdgcn_mfma_f32_32x32x16_bf16(kf[3], qf1[3], bB, 0, 0, 0);
    __builtin_amdgcn_s_setprio(0);

    // combine halves + branchless causal mask:
    // mask element iff (g-limc)*32 + kvl - l31 > 0  <=>  dgc > l31 - kvl
    #pragma unroll
    for (int r = 0; r < 16; ++r) {
        int kvl = (r&3) + 8*(r>>2) + 4*hi;
        int thr = l31 - kvl;
        float v0 = aA[r] + aB[r];
        float v1 = bA[r] + bB[r];
        aA[r] = (dg0 > thr) ? -1e30f : v0;
        bA[r] = (dg1 > thr) ? -1e30f : v1;
    }

    // row max, both chains (independent trees)
    float p0a = fmaxf(aA[0], aA[1]),   p0b = fmaxf(aA[2], aA[3]);
    float p0c = fmaxf(aA[4], aA[5]),   p0d = fmaxf(aA[6], aA[7]);
    float p0e = fmaxf(aA[8], aA[9]),   p0f = fmaxf(aA[10], aA[11]);
    float p0g = fmaxf(aA[12], aA[13]), p0h = fmaxf(aA[14], aA[15]);
    float pm0 = fmaxf(fmaxf(fmaxf(p0a, p0b), fmaxf(p0c, p0d)),
                      fmaxf(fmaxf(p0e, p0f), fmaxf(p0g, p0h)));
    float p1a = fmaxf(bA[0], bA[1]),   p1b = fmaxf(bA[2], bA[3]);
    float p1c = fmaxf(bA[4], bA[5]),   p1d = fmaxf(bA[6], bA[7]);
    float p1e = fmaxf(bA[8], bA[9]),   p1f = fmaxf(bA[10], bA[11]);
    float p1g = fmaxf(bA[12], bA[13]), p1h = fmaxf(bA[14], bA[15]);
    float pm1 = fmaxf(fmaxf(fmaxf(p1a, p1b), fmaxf(p1c, p1d)),
                      fmaxf(fmaxf(p1e, p1f), fmaxf(p1g, p1h)));
    pm0 = xhalf_max(pm0);
    pm1 = xhalf_max(pm1);

    // combined defer-max (T13): single wave-uniform branch for both chains
    if (!__all((pm0 - m0 <= 8.0f) && (pm1 - m1 <= 8.0f))) {
        float mn0 = fmaxf(m0, pm0);
        float mn1 = fmaxf(m1, pm1);
        float al0 = fexp2(m0 - mn0);
        float al1 = fexp2(m1 - mn1);
        l0 *= al0; m0 = mn0;
        l1 *= al1; m1 = mn1;
        #pragma unroll
        for (int r = 0; r < 16; ++r) {
            int row = (r&3) + 8*(r>>2) + 4*hi;
            float a0r = __shfl(al0, row);
            float a1r = __shfl(al1, row);
            o00[r] *= a0r; o01[r] *= a0r;
            o10[r] *= a1r; o11[r] *= a1r;
        }
    }

    // P = exp2(s - m), both chains
    #pragma unroll
    for (int r = 0; r < 16; ++r) {
        aA[r] = fexp2(aA[r] - m0);
        bA[r] = fexp2(bA[r] - m1);
    }
    float s0a = aA[0]+aA[1],  s0b = aA[2]+aA[3],  s0c = aA[4]+aA[5],   s0d = aA[6]+aA[7];
    float s0e = aA[8]+aA[9],  s0f = aA[10]+aA[11], s0g = aA[12]+aA[13], s0h = aA[14]+aA[15];
    float rs0 = ((s0a+s0b) + (s0c+s0d)) + ((s0e+s0f) + (s0g+s0h));
    float s1a = bA[0]+bA[1],  s1b = bA[2]+bA[3],  s1c = bA[4]+bA[5],   s1d = bA[6]+bA[7];
    float s1e = bA[8]+bA[9],  s1f = bA[10]+bA[11], s1g = bA[12]+bA[13], s1h = bA[14]+bA[15];
    float rs1 = ((s1a+s1b) + (s1c+s1d)) + ((s1e+s1f) + (s1g+s1h));
    rs0 = xhalf_sum(rs0);
    rs1 = xhalf_sum(rs1);
    l0 += rs0;
    l1 += rs1;

    // pack P to bf16 pairs, both chains
    unsigned pk0[8], pk1[8];
    #pragma unroll
    for (int jj = 0; jj < 8; ++jj) {
        pk0[jj] = cvtpk_bf16(aA[2*jj], aA[2*jj+1]);
        pk1[jj] = cvtpk_bf16(bA[2*jj], bA[2*jj+1]);
    }

    // PV: 4 independent accumulator chains
    #pragma unroll
    for (int kb = 0; kb < 2; ++kb) {
        unsigned f0x = pk0[4*kb+0], f0z = pk0[4*kb+2];
        unsigned f0y = pk0[4*kb+1], f0w = pk0[4*kb+3];
        plswap(f0x, f0z); plswap(f0y, f0w);
        u32x4 w0; w0.x = f0x; w0.y = f0y; w0.z = f0z; w0.w = f0w;
        short8 pf0 = __builtin_bit_cast(short8, w0);
        unsigned f1x = pk1[4*kb+0], f1z = pk1[4*kb+2];
        unsigned f1y = pk1[4*kb+1], f1w = pk1[4*kb+3];
        plswap(f1x, f1z); plswap(f1y, f1w);
        u32x4 w1; w1.x = f1x; w1.y = f1y; w1.z = f1z; w1.w = f1w;
        short8 pf1 = __builtin_bit_cast(short8, w1);
        __builtin_amdgcn_s_setprio(1);
        o00 = __builtin_amdgcn_mfma_f32_32x32x16_bf16(pf0, vlo[kb], o00, 0, 0, 0);
        o10 = __builtin_amdgcn_mfma_f32_32x32x16_bf16(pf1, vlo[kb], o10, 0, 0, 0);
        o01 = __builtin_amdgcn_mfma_f32_32x32x16_bf16(pf0, vhi[kb], o01, 0, 0, 0);
        o11 = __builtin_amdgcn_mfma_f32_32x32x16_bf16(pf1, vhi[kb], o11, 0, 0, 0);
        __builtin_amdgcn_s_setprio(0);
    }
}

__global__ __launch_bounds__(256, 2) void flash_attn(
    const unsigned short* __restrict__ q,
    const unsigned short* __restrict__ k,
    const unsigned short* __restrict__ vt,
    unsigned short* __restrict__ y)
{
    // staging: [buf][tensor][4096 shorts]; tensors: 0=K_lo 1=K_hi 2=V_lo 3=V_hi (64 KB)
    __shared__ __align__(16) unsigned short ST[2][4][4096];
    // merge overlay (used only after the final compute barrier):
    float* oP  = reinterpret_cast<float*>(&ST[0][0][0]);   // [4 sets][32 rows][68]
    float* mlP = oP + 4*32*68;                             // m: [set*32+l31], l: +128

    int tid = threadIdx.x, lane = tid & 63, w = tid >> 6;
    int l31 = lane & 31, hi = lane >> 5, rsw = l31 & 7;
    int role = w >> 1, pair = w & 1;
    int bid = blockIdx.x;

    // balanced complementary mapping: co-resident blocks (bid, bid+256) have S summing to 15
    int half = bid >> 8;              // 0 or 1
    int idx  = bid & 255;
    int bh   = (idx & 7)*4 + ((idx >> 3) & 3);   // 4 heads per XCD
    int sidx = idx >> 5;              // 0..7
    int S    = half ? sidx : (15 - sidx);        // heavy half first

    const unsigned short* kp = k  + (size_t)bh*T_*D_;
    const unsigned short* vp = vt + (size_t)bh*D_*T_;

    int rowbase = S*128 + pair*64;    // this wave-pair's first q row
    const unsigned short* qp = q + ((size_t)bh*T_ + rowbase) * D_;

    short8 qf0[4], qf1[4];
    #pragma unroll
    for (int dk = 0; dk < 4; ++dk) {
        qf0[dk] = *reinterpret_cast<const short8*>(qp + (size_t)l31*D_        + dk*16 + hi*8);
        qf1[dk] = *reinterpret_cast<const short8*>(qp + (size_t)(32 + l31)*D_ + dk*16 + hi*8);
    }

    f32x16 o00 = {}, o01 = {}, o10 = {}, o11 = {};
    float m0 = -1e29f, l0 = 0.f, m1 = -1e29f, l1 = 0.f;   // sentinel > mask value

    int lim0 = 4*S + 2*pair;          // chain0 diag sub-tile (global g)
    int lim1 = lim0 + 1;              // chain1
    int niter = S + 1;                // tiles per stream

    // stage iteration ii: low tile = ii, high tile = S+1+ii (512 chunks/tensor)
    #define STAGE(ii, bufi)                                                            \
    {                                                                                  \
        _Pragma("unroll")                                                              \
        for (int jj = 0; jj < 2; ++jj) {                                               \
            int c2 = tid + jj*256;                                                     \
            int row_ = c2 >> 3;                                                        \
            int slot_ = (c2 & 7) ^ (row_ & 7);                                         \
            int tl_ = (ii), th_ = S + 1 + (ii);                                        \
            gload16(kp + ((size_t)(tl_*64 + row_))*D_ + slot_*8, &ST[bufi][0][c2*8]);  \
            gload16(kp + ((size_t)(th_*64 + row_))*D_ + slot_*8, &ST[bufi][1][c2*8]);  \
            gload16(vp + (size_t)row_*T_ + tl_*64 + slot_*8,     &ST[bufi][2][c2*8]);  \
            gload16(vp + (size_t)row_*T_ + th_*64 + slot_*8,     &ST[bufi][3][c2*8]);  \
        }                                                                              \
    }

    STAGE(0, 0);
    __syncthreads();

    for (int i = 0; i < niter; ++i) {
        int bufi = i & 1;
        if (i + 1 < niter) STAGE(i + 1, bufi ^ 1);

        const unsigned short* Kl = &ST[bufi][role][0];
        const unsigned short* Vl = &ST[bufi][2 + role][0];
        int t = role ? (S + 1 + i) : i;

        #pragma unroll
        for (int st = 0; st < 2; ++st) {
            int g = 2*t + st;
            if (g <= lim1) {
                short8 kf[4];
                const unsigned short* kr = Kl + (st*32 + l31)*64;
                #pragma unroll
                for (int dk = 0; dk < 4; ++dk)
                    kf[dk] = *reinterpret_cast<const short8*>(kr + (((dk<<1)|hi) ^ rsw)*8);
                short8 vlo[2], vhi[2];
                const unsigned short* vr0 = Vl + l31*64;
                const unsigned short* vr1 = Vl + (32 + l31)*64;
                #pragma unroll
                for (int kb = 0; kb < 2; ++kb) {
                    int sl = (((st<<2) | (kb<<1) | hi) ^ rsw) * 8;
                    vlo[kb] = *reinterpret_cast<const short8*>(vr0 + sl);
                    vhi[kb] = *reinterpret_cast<const short8*>(vr1 + sl);
                }
                int dg0 = (g - lim0) << 5;
                attn_subtile2(kf, qf0, qf1, vlo, vhi, dg0, l31, hi,
                              o00, o01, m0, l0, o10, o11, m1, l1);
            }
        }
        __syncthreads();
    }
    #undef STAGE

    // ---- merge the two KV halves (low waves store; high waves combine + write) ----
    if (!role) {
        int s0 = pair*2, s1 = pair*2 + 1;
        #pragma unroll
        for (int rr = 0; rr < 16; ++rr) {
            int crow = (rr&3) + 8*(rr>>2) + 4*hi;
            oP[(s0*32 + crow)*68 + l31]      = o00[rr];
            oP[(s0*32 + crow)*68 + 32 + l31] = o01[rr];
            oP[(s1*32 + crow)*68 + l31]      = o10[rr];
            oP[(s1*32 + crow)*68 + 32 + l31] = o11[rr];
        }
        if (!hi) {
            mlP[s0*32 + l31]       = m0;
            mlP[128 + s0*32 + l31] = l0;
            mlP[s1*32 + l31]       = m1;
            mlP[128 + s1*32 + l31] = l1;
        }
    }
    __syncthreads();
    if (role) {
        int b = bh >> 4, h = bh & 15;
        #pragma unroll
        for (int qq = 0; qq < 2; ++qq) {
            int set = pair*2 + qq;
            const f32x16& po0 = qq ? o10 : o00;
            const f32x16& po1 = qq ? o11 : o01;
            float m_ = qq ? m1 : m0;
            float l_ = qq ? l1 : l0;

            float mA = mlP[set*32 + l31];
            float lA = mlP[128 + set*32 + l31];
            float mN = fmaxf(mA, m_);
            float aA = fexp2(mA - mN);
            float aB = fexp2(m_ - mN);
            float lN = lA*aA + l_*aB;
            float inv = 1.0f / lN;
            float cA = aA * inv, cB = aB * inv;

            #pragma unroll
            for (int rr = 0; rr < 16; ++rr) {
                int crow = (rr&3) + 8*(rr>>2) + 4*hi;
                float cAr = __shfl(cA, crow);
                float cBr = __shfl(cB, crow);
                float vA0 = oP[(set*32 + crow)*68 + l31];
                float vA1 = oP[(set*32 + crow)*68 + 32 + l31];
                int trow = rowbase + qq*32 + crow;
                size_t base = ((size_t)(b*T_ + trow))*C_ + h*64;
                y[base + l31]      = f2bf(vA0*cAr + po0[rr]*cBr);
                y[base + 32 + l31] = f2bf(vA1*cAr + po1[rr]*cBr);
            }
        }
    }
}

extern "C" void kernel_launch(void* const* d_in, const int* in_sizes, int n_in,
                              void* d_out, int out_size, void* d_ws, size_t ws_size,
                              hipStream_t stream) {
    const float* x  = (const float*)d_in[0];
    const float* Wk = (const float*)d_in[1];
    const float* bk = (const float*)d_in[2];
    const float* Wq = (const float*)d_in[3];
    const float* bq = (const float*)d_in[4];
    const float* Wv = (const float*)d_in[5];
    const float* bv = (const float*)d_in[6];
    const float* Wo = (const float*)d_in[7];
    const float* bo = (const float*)d_in[8];
    float* out = (float*)d_out;

    char* ws = (char*)d_ws;
    unsigned short* xb  = (unsigned short*)(ws);                    // 8MB
    unsigned short* wkb = (unsigned short*)(ws + ((size_t)8  << 20));
    unsigned short* wqb = (unsigned short*)(ws + ((size_t)10 << 20));
    unsigned short* wvb = (unsigned short*)(ws + ((size_t)12 << 20));
    unsigned short* wob = (unsigned short*)(ws + ((size_t)14 << 20));
    unsigned short* qb  = (unsigned short*)(ws + ((size_t)16 << 20)); // [B,H,T,D]
    unsigned short* kb  = (unsigned short*)(ws + ((size_t)24 << 20)); // [B,H,T,D]
    unsigned short* vtb = (unsigned short*)(ws + ((size_t)32 << 20)); // [B,H,D,T]
    unsigned short* yb  = (unsigned short*)(ws + ((size_t)40 << 20)); // [B*T,C]

    cvt_all<<<dim3(8192), dim3(256), 0, stream>>>(
        x, Wk, Wq, Wv, Wo, xb, wkb, wqb, wvb, wob);

    gemm_qkv<<<dim3(768), dim3(256), 0, stream>>>(xb, wkb, wqb, wvb, bk, bq, bv, kb, qb, vtb);

    flash_attn<<<dim3(512), dim3(256), 0, stream>>>(qb, kb, vtb, yb);

    gemm_out<<<dim3(256), dim3(256), 0, stream>>>(yb, wob, bo, out);
}